// Round 1
// baseline (86.737 us; speedup 1.0000x reference)
//
#include <hip/hip_runtime.h>

// CostVolume3D: B=8 H=128 W=256 C=8, D=23 disparity hypotheses.
//
// Key identity: tiling [..., 1] -> [..., D] along a NEW LAST axis then doing a
// raw row-major reshape gives tiled_flat[i] = src_flat[i / D]. So the whole
// scrambled TF graph reduces to integer div-by-23 indexing:
//   out_flat[L]       (L over [B*D, H, W], identical to final [B,H,W,D] flat)
//   disp  = wflow_flat[L/23] - ((L>>15) % 23 - 11)
//   A_c   = feat_l_flat[(L*8 + c) / 23]
//   V_c@x = feat_r_flat[((rowbase + x)*8 + c) / 23]
// 8 consecutive numerators / 23 hit at most 2 quotients -> load lo/hi pair
// per tensor and cndmask-select per channel at switch point s = 23 - base%23.

#define BB 8
#define HH 128
#define WW 256
#define CC 8
#define DD 23
#define NOUT (BB * HH * WW * DD)          // 6,029,312
#define FEAT_MAXQ (BB * HH * WW * CC - 1) // 2,097,151

__global__ __launch_bounds__(256) void costvol_kernel(
    const float* __restrict__ feat_l,
    const float* __restrict__ feat_r,
    const float* __restrict__ wflow,
    float* __restrict__ out)
{
    unsigned L = blockIdx.x * 256u + threadIdx.x;
    if (L >= (unsigned)NOUT) return;

    unsigned n  = L >> 15;         // / (H*W)
    unsigned wp = L & (WW - 1);

    // shift = (n % 23) - 11  (STRIDE=1)
    unsigned nmod = n % 23u;
    float shiftf = (float)(int)nmod - 11.0f;

    float disp = wflow[L / 23u] - shiftf;
    float xq   = (float)wp - disp;
    float x0f  = floorf(xq);
    float frac = xq - x0f;                 // w1, NOT clipped (matches ref)
    int x0i = (int)x0f;
    x0i = min(max(x0i, 0), WW - 1);
    int x1i = min(x0i + 1, WW - 1);

    unsigned rowbase = L - wp;             // (n*H + hp) * W
    unsigned baseL = L * 8u;
    unsigned base0 = (rowbase + (unsigned)x0i) * 8u;
    unsigned base1 = (rowbase + (unsigned)x1i) * 8u;

    unsigned qL = baseL / 23u; unsigned rL = baseL - qL * 23u;
    unsigned q0 = base0 / 23u; unsigned r0 = base0 - q0 * 23u;
    unsigned q1 = base1 / 23u; unsigned r1 = base1 - q1 * 23u;

    float aLo  = feat_l[qL];
    float aHi  = feat_l[min(qL + 1u, (unsigned)FEAT_MAXQ)];
    float b0Lo = feat_r[q0];
    float b0Hi = feat_r[min(q0 + 1u, (unsigned)FEAT_MAXQ)];
    float b1Lo = feat_r[q1];
    float b1Hi = feat_r[min(q1 + 1u, (unsigned)FEAT_MAXQ)];

    int sL = 23 - (int)rL;   // channel c uses "lo" iff c < s
    int s0 = 23 - (int)r0;
    int s1 = 23 - (int)r1;

    float one_m = 1.0f - frac;
    float acc = 0.0f;
    #pragma unroll
    for (int c = 0; c < 8; ++c) {
        float A  = (c < sL) ? aLo  : aHi;
        float V0 = (c < s0) ? b0Lo : b0Hi;
        float V1 = (c < s1) ? b1Lo : b1Hi;
        float wv = V0 * one_m + V1 * frac;   // v0*(1-w1) + v1*w1
        acc += fabsf(A - wv);
    }
    out[L] = acc;
}

extern "C" void kernel_launch(void* const* d_in, const int* in_sizes, int n_in,
                              void* d_out, int out_size, void* d_ws, size_t ws_size,
                              hipStream_t stream) {
    const float* feat_l = (const float*)d_in[0];
    const float* feat_r = (const float*)d_in[1];
    const float* wflow  = (const float*)d_in[2];
    float* out = (float*)d_out;

    const int threads = 256;
    const int blocks  = (NOUT + threads - 1) / threads;  // 23552
    costvol_kernel<<<blocks, threads, 0, stream>>>(feat_l, feat_r, wflow, out);
}